// Round 2
// baseline (65.630 us; speedup 1.0000x reference)
//
#include <hip/hip_runtime.h>

// GeneralPulling (all f32):
//   D_ap = ||emb[anc]-ref[pos]||, D_an = ||emb[anc]-ref[neg]||  (clip >= 1e-6)
//   lam_eta = edge[anc,neg,:] * exp(-1/J_avg)   (J_avg==0 -> x=1e6)
//   r = (1-lam_eta)*(D_ap/D_an) + lam_eta
//   z_hat = (D_ap >= D_an) ? ref[neg] : (1-r)*emb[anc] + r*ref[neg]
//
// 32 lanes per t, one float4 per lane -> 512 B coalesced row accesses.

typedef __attribute__((ext_vector_type(4))) float float4_t;

#define NB  128   // NBITS
#define TPB 8     // t's per block (256 threads / 32 lanes-per-t)

__global__ __launch_bounds__(256) void general_pulling_kernel(
    const float* __restrict__ emb,    // [B,128] f32
    const float* __restrict__ refe,   // [B,128] f32
    const int*   __restrict__ anc_idx,
    const int*   __restrict__ pos_idx,
    const int*   __restrict__ neg_idx,
    const float* __restrict__ edge,   // [B,B,128] f32
    const float* __restrict__ javg_p, // [1] f32
    float*       __restrict__ out,    // [T,128] f32
    int T, int B)
{
    const int tid = threadIdx.x;
    const int g   = tid >> 5;     // which t within block
    const int sub = tid & 31;     // lane within 32-lane group
    const int t   = blockIdx.x * TPB + g;
    if (t >= T) return;

    const int anc = anc_idx[t];
    const int pos = pos_idx[t];
    const int neg = neg_idx[t];

    // Issue the streaming edge-row gather as early as possible (HBM latency).
    const float4_t le = *(const float4_t*)(edge + ((size_t)anc * B + neg) * NB + sub * 4);

    // L2-resident table reads (1 MB total).
    const float4_t ea = *(const float4_t*)(emb  + (size_t)anc * NB + sub * 4);
    const float4_t rp = *(const float4_t*)(refe + (size_t)pos * NB + sub * 4);
    const float4_t rn = *(const float4_t*)(refe + (size_t)neg * NB + sub * 4);

    // scale = exp(-ALPHA/x), x = (J_avg==0 ? 1e6 : J_avg), ALPHA=1
    const float javg  = javg_p[0];
    const float x     = (javg == 0.0f) ? 1e6f : javg;
    const float scale = expf(-1.0f / x);

    float sap = 0.0f, san = 0.0f;
    #pragma unroll
    for (int k = 0; k < 4; ++k) {
        const float dp = ea[k] - rp[k];
        const float dn = ea[k] - rn[k];
        sap += dp * dp;
        san += dn * dn;
    }
    // butterfly reduce across the 32-lane group (32-aligned inside wave64,
    // so xor masks 1..16 never cross the group boundary)
    #pragma unroll
    for (int m = 1; m < 32; m <<= 1) {
        sap += __shfl_xor(sap, m, 64);
        san += __shfl_xor(san, m, 64);
    }

    float D_ap = sqrtf(fmaxf(sap, 0.0f)); D_ap = fmaxf(D_ap, 1e-6f);
    float D_an = sqrtf(fmaxf(san, 0.0f)); D_an = fmaxf(D_an, 1e-6f);
    const bool  negmask = (D_ap >= D_an);
    const float ratio   = D_ap / D_an;

    float4_t o;
    #pragma unroll
    for (int k = 0; k < 4; ++k) {
        const float lam = le[k] * scale;                // lambda_eta
        const float r   = ratio + lam * (1.0f - ratio); // (1-lam)*ratio + lam
        const float z   = ea[k] + r * (rn[k] - ea[k]);  // (1-r)*zi + r*zj
        o[k] = negmask ? rn[k] : z;
    }
    *(float4_t*)(out + (size_t)t * NB + sub * 4) = o;
}

extern "C" void kernel_launch(void* const* d_in, const int* in_sizes, int n_in,
                              void* d_out, int out_size, void* d_ws, size_t ws_size,
                              hipStream_t stream) {
    const float* emb  = (const float*)d_in[0];
    const float* refe = (const float*)d_in[1];
    const int*   anc  = (const int*)d_in[2];
    const int*   pos  = (const int*)d_in[3];
    const int*   neg  = (const int*)d_in[4];
    const float* edge = (const float*)d_in[5];
    const float* javg = (const float*)d_in[6];
    float*       out  = (float*)d_out;

    const int T = in_sizes[2];           // 262144
    const int B = in_sizes[0] / NB;      // 1024

    const int blocks = (T + TPB - 1) / TPB;
    general_pulling_kernel<<<blocks, 256, 0, stream>>>(
        emb, refe, anc, pos, neg, edge, javg, out, T, B);
}

// Round 3
// 64.541 us; speedup vs baseline: 1.0169x; 1.0169x over previous
//
#include <hip/hip_runtime.h>

// GeneralPulling (all f32):
//   D_ap = ||emb[anc]-ref[pos]||, D_an = ||emb[anc]-ref[neg]||  (clip >= 1e-6)
//   lam_eta = edge[anc,neg,:] * exp(-1/J_avg)   (J_avg==0 -> x=1e6)
//   r = (1-lam_eta)*(D_ap/D_an) + lam_eta
//   z_hat = (D_ap >= D_an) ? ref[neg] : (1-r)*emb[anc] + r*ref[neg]
//
// 32 lanes per t, one float4 per lane -> 512 B coalesced row accesses.
// 2 t's per thread (t0 = base+g, t1 = t0+8): doubles in-flight gathers per
// wave (MLP) to test the latency-bound hypothesis.

typedef __attribute__((ext_vector_type(4))) float float4_t;

#define NB  128   // NBITS
#define TPB 16    // t's per block (8 groups x 2 t's each)

__global__ __launch_bounds__(256) void general_pulling_kernel(
    const float* __restrict__ emb,    // [B,128] f32
    const float* __restrict__ refe,   // [B,128] f32
    const int*   __restrict__ anc_idx,
    const int*   __restrict__ pos_idx,
    const int*   __restrict__ neg_idx,
    const float* __restrict__ edge,   // [B,B,128] f32
    const float* __restrict__ javg_p, // [1] f32
    float*       __restrict__ out,    // [T,128] f32
    int T, int B)
{
    const int tid = threadIdx.x;
    const int g   = tid >> 5;     // group within block (0..7)
    const int sub = tid & 31;     // lane within 32-lane group
    const int t0  = blockIdx.x * TPB + g;
    const int t1  = t0 + 8;
    if (t1 >= T) {                // T % 16 == 0 in practice; guard anyway
        if (t0 >= T) return;
    }

    const int anc0 = anc_idx[t0], pos0 = pos_idx[t0], neg0 = neg_idx[t0];
    const int anc1 = anc_idx[t1], pos1 = pos_idx[t1], neg1 = neg_idx[t1];

    // Issue both streaming edge-row gathers first (HBM latency, 2x MLP).
    const float4_t le0 = *(const float4_t*)(edge + ((size_t)anc0 * B + neg0) * NB + sub * 4);
    const float4_t le1 = *(const float4_t*)(edge + ((size_t)anc1 * B + neg1) * NB + sub * 4);

    // L2-resident table reads (1 MB total).
    const float4_t ea0 = *(const float4_t*)(emb  + (size_t)anc0 * NB + sub * 4);
    const float4_t rp0 = *(const float4_t*)(refe + (size_t)pos0 * NB + sub * 4);
    const float4_t rn0 = *(const float4_t*)(refe + (size_t)neg0 * NB + sub * 4);
    const float4_t ea1 = *(const float4_t*)(emb  + (size_t)anc1 * NB + sub * 4);
    const float4_t rp1 = *(const float4_t*)(refe + (size_t)pos1 * NB + sub * 4);
    const float4_t rn1 = *(const float4_t*)(refe + (size_t)neg1 * NB + sub * 4);

    // scale = exp(-ALPHA/x), x = (J_avg==0 ? 1e6 : J_avg), ALPHA=1
    const float javg  = javg_p[0];
    const float x     = (javg == 0.0f) ? 1e6f : javg;
    const float scale = expf(-1.0f / x);

    float sap0 = 0.0f, san0 = 0.0f, sap1 = 0.0f, san1 = 0.0f;
    #pragma unroll
    for (int k = 0; k < 4; ++k) {
        float dp0 = ea0[k] - rp0[k], dn0 = ea0[k] - rn0[k];
        float dp1 = ea1[k] - rp1[k], dn1 = ea1[k] - rn1[k];
        sap0 += dp0 * dp0;  san0 += dn0 * dn0;
        sap1 += dp1 * dp1;  san1 += dn1 * dn1;
    }
    // butterfly reduce across the 32-lane group (32-aligned inside wave64)
    #pragma unroll
    for (int m = 1; m < 32; m <<= 1) {
        sap0 += __shfl_xor(sap0, m, 64);
        san0 += __shfl_xor(san0, m, 64);
        sap1 += __shfl_xor(sap1, m, 64);
        san1 += __shfl_xor(san1, m, 64);
    }

    float D_ap0 = fmaxf(sqrtf(fmaxf(sap0, 0.0f)), 1e-6f);
    float D_an0 = fmaxf(sqrtf(fmaxf(san0, 0.0f)), 1e-6f);
    float D_ap1 = fmaxf(sqrtf(fmaxf(sap1, 0.0f)), 1e-6f);
    float D_an1 = fmaxf(sqrtf(fmaxf(san1, 0.0f)), 1e-6f);
    const bool  negmask0 = (D_ap0 >= D_an0), negmask1 = (D_ap1 >= D_an1);
    const float ratio0   = D_ap0 / D_an0,    ratio1   = D_ap1 / D_an1;

    float4_t o0, o1;
    #pragma unroll
    for (int k = 0; k < 4; ++k) {
        const float lam0 = le0[k] * scale;
        const float r0   = ratio0 + lam0 * (1.0f - ratio0);
        const float z0   = ea0[k] + r0 * (rn0[k] - ea0[k]);
        o0[k] = negmask0 ? rn0[k] : z0;

        const float lam1 = le1[k] * scale;
        const float r1   = ratio1 + lam1 * (1.0f - ratio1);
        const float z1   = ea1[k] + r1 * (rn1[k] - ea1[k]);
        o1[k] = negmask1 ? rn1[k] : z1;
    }
    *(float4_t*)(out + (size_t)t0 * NB + sub * 4) = o0;
    *(float4_t*)(out + (size_t)t1 * NB + sub * 4) = o1;
}

extern "C" void kernel_launch(void* const* d_in, const int* in_sizes, int n_in,
                              void* d_out, int out_size, void* d_ws, size_t ws_size,
                              hipStream_t stream) {
    const float* emb  = (const float*)d_in[0];
    const float* refe = (const float*)d_in[1];
    const int*   anc  = (const int*)d_in[2];
    const int*   pos  = (const int*)d_in[3];
    const int*   neg  = (const int*)d_in[4];
    const float* edge = (const float*)d_in[5];
    const float* javg = (const float*)d_in[6];
    float*       out  = (float*)d_out;

    const int T = in_sizes[2];           // 262144
    const int B = in_sizes[0] / NB;      // 1024

    const int blocks = (T + TPB - 1) / TPB;
    general_pulling_kernel<<<blocks, 256, 0, stream>>>(
        emb, refe, anc, pos, neg, edge, javg, out, T, B);
}